// Round 9
// baseline (867.368 us; speedup 1.0000x reference)
//
#include <hip/hip_runtime.h>
#include <hip/hip_bf16.h>
#include <hip/hip_cooperative_groups.h>

namespace cg = cooperative_groups;

#define N_NODES  100000
#define N_EDGES  600000
#define D        128
#define N_GRAPHS 512

#define CH   512
#define NB   ((N_NODES + CH - 1) / CH)   // 196

typedef __attribute__((ext_vector_type(8))) short      short8v;
typedef __attribute__((ext_vector_type(4))) float      f32x4;

// float -> bf16 (RNE) on raw bits
__device__ __forceinline__ unsigned short f2bf(float f) {
    unsigned int u = __float_as_uint(f);
    u += 0x7fffu + ((u >> 16) & 1u);
    return (unsigned short)(u >> 16);
}
__device__ __forceinline__ float bflo2f(unsigned int p) { return __uint_as_float(p << 16); }
__device__ __forceinline__ float bfhi2f(unsigned int p) { return __uint_as_float(p & 0xffff0000u); }

// ---------------------------------------------------------------------------
// GEMM phase (device function): Y[bf16] = (RELU_IN ? relu(X) : X) @ W via
// 16x16x32 bf16 MFMA, split-precision W (hi+lo) staged on the fly into LDS.
// 512 thr / 8 waves; each tile = 256 rows. 1-kc-ahead load pipeline keeps
// VGPR <= 128 (launch_bounds cap) while hiding vmem latency behind MFMA.
// Operands swapped (W first) -> D holds Y^T -> packed 8-B bf16 column stores.
// ---------------------------------------------------------------------------
template<int RELU_IN, int SPLIT_X>
__device__ __forceinline__ void gemm_phase(const void* __restrict__ Xv,
                                           const float* __restrict__ W,
                                           short* __restrict__ wl_hi,
                                           short* __restrict__ wl_lo,
                                           unsigned short* __restrict__ Y) {
    const int tid = threadIdx.x;

    // stage W fragments with on-the-fly hi/lo split (W is 64KB, L2-hot)
    for (int t = tid; t < 2048; t += 512) {
        int lane = t & 63, cb = (t >> 6) & 7, kc = t >> 9;
        int krow = kc * 32 + ((lane >> 4) * 8);
        int col  = cb * 16 + (lane & 15);
        short8v h8, l8;
        #pragma unroll
        for (int j = 0; j < 8; ++j) {
            float f = W[(krow + j) * D + col];
            unsigned short h = f2bf(f);
            float hf = __uint_as_float(((unsigned int)h) << 16);
            h8[j] = (short)h;
            l8[j] = (short)f2bf(f - hf);
        }
        *(short8v*)&wl_hi[t * 8] = h8;
        *(short8v*)&wl_lo[t * 8] = l8;
    }
    __syncthreads();

    const int wave = tid >> 6;
    const int lane = tid & 63;
    const int lrow = lane & 15;
    const int kgrp = lane >> 4;
    const int ntiles = (N_NODES + 255) / 256;
    const float*          Xf = (const float*)Xv;
    const unsigned short* Xb = (const unsigned short*)Xv;

    for (int tile = blockIdx.x; tile < ntiles; tile += gridDim.x) {
        const int row_base = tile * 256 + wave * 32;

        f32x4 acc[2][8];
        #pragma unroll
        for (int rg = 0; rg < 2; ++rg)
            #pragma unroll
            for (int cb = 0; cb < 8; ++cb)
                acc[rg][cb] = (f32x4){0.f, 0.f, 0.f, 0.f};

        if (SPLIT_X) {
            float4 cur[2][2];
            #pragma unroll
            for (int rg = 0; rg < 2; ++rg) {
                int row = row_base + rg * 16 + lrow;
                if (row < N_NODES) {
                    const float* p = Xf + (size_t)row * D + kgrp * 8;
                    cur[rg][0] = *(const float4*)p;
                    cur[rg][1] = *(const float4*)(p + 4);
                } else {
                    cur[rg][0] = make_float4(0.f, 0.f, 0.f, 0.f);
                    cur[rg][1] = make_float4(0.f, 0.f, 0.f, 0.f);
                }
            }
            #pragma unroll
            for (int kc = 0; kc < 4; ++kc) {
                float4 nxt[2][2];
                if (kc < 3) {
                    #pragma unroll
                    for (int rg = 0; rg < 2; ++rg) {
                        int row = row_base + rg * 16 + lrow;
                        if (row < N_NODES) {
                            const float* p = Xf + (size_t)row * D + (kc + 1) * 32 + kgrp * 8;
                            nxt[rg][0] = *(const float4*)p;
                            nxt[rg][1] = *(const float4*)(p + 4);
                        } else {
                            nxt[rg][0] = make_float4(0.f, 0.f, 0.f, 0.f);
                            nxt[rg][1] = make_float4(0.f, 0.f, 0.f, 0.f);
                        }
                    }
                } else {
                    nxt[0][0] = cur[0][0]; nxt[0][1] = cur[0][1];
                    nxt[1][0] = cur[1][0]; nxt[1][1] = cur[1][1];
                }
                short8v xh[2], xl[2];
                #pragma unroll
                for (int rg = 0; rg < 2; ++rg) {
                    float fv[8] = {cur[rg][0].x, cur[rg][0].y, cur[rg][0].z, cur[rg][0].w,
                                   cur[rg][1].x, cur[rg][1].y, cur[rg][1].z, cur[rg][1].w};
                    #pragma unroll
                    for (int j = 0; j < 8; ++j) {
                        float f = RELU_IN ? fmaxf(fv[j], 0.f) : fv[j];
                        unsigned short h = f2bf(f);
                        float hf = __uint_as_float(((unsigned int)h) << 16);
                        xh[rg][j] = (short)h;
                        xl[rg][j] = (short)f2bf(f - hf);
                    }
                }
                #pragma unroll
                for (int cb = 0; cb < 8; ++cb) {
                    const int fo = ((kc * 8 + cb) * 64 + lane) * 8;
                    short8v bh = *(const short8v*)&wl_hi[fo];
                    short8v bl = *(const short8v*)&wl_lo[fo];
                    #pragma unroll
                    for (int rg = 0; rg < 2; ++rg) {
                        acc[rg][cb] = __builtin_amdgcn_mfma_f32_16x16x32_bf16(bh, xh[rg], acc[rg][cb], 0, 0, 0);
                        acc[rg][cb] = __builtin_amdgcn_mfma_f32_16x16x32_bf16(bl, xh[rg], acc[rg][cb], 0, 0, 0);
                        acc[rg][cb] = __builtin_amdgcn_mfma_f32_16x16x32_bf16(bh, xl[rg], acc[rg][cb], 0, 0, 0);
                    }
                }
                cur[0][0] = nxt[0][0]; cur[0][1] = nxt[0][1];
                cur[1][0] = nxt[1][0]; cur[1][1] = nxt[1][1];
            }
        } else {
            short8v cur[2];
            #pragma unroll
            for (int rg = 0; rg < 2; ++rg) {
                int row = row_base + rg * 16 + lrow;
                short8v v = {0, 0, 0, 0, 0, 0, 0, 0};
                if (row < N_NODES)
                    v = *(const short8v*)(Xb + (size_t)row * D + kgrp * 8);
                cur[rg] = v;
            }
            #pragma unroll
            for (int kc = 0; kc < 4; ++kc) {
                short8v nxt[2];
                if (kc < 3) {
                    #pragma unroll
                    for (int rg = 0; rg < 2; ++rg) {
                        int row = row_base + rg * 16 + lrow;
                        short8v v = {0, 0, 0, 0, 0, 0, 0, 0};
                        if (row < N_NODES)
                            v = *(const short8v*)(Xb + (size_t)row * D + (kc + 1) * 32 + kgrp * 8);
                        nxt[rg] = v;
                    }
                } else {
                    nxt[0] = cur[0]; nxt[1] = cur[1];
                }
                short8v xh[2];
                #pragma unroll
                for (int rg = 0; rg < 2; ++rg) {
                    short8v v = cur[rg];
                    if (RELU_IN) {
                        #pragma unroll
                        for (int j = 0; j < 8; ++j)
                            if (((unsigned short)v[j]) & 0x8000u) v[j] = 0;
                    }
                    xh[rg] = v;
                }
                #pragma unroll
                for (int cb = 0; cb < 8; ++cb) {
                    const int fo = ((kc * 8 + cb) * 64 + lane) * 8;
                    short8v bh = *(const short8v*)&wl_hi[fo];
                    short8v bl = *(const short8v*)&wl_lo[fo];
                    #pragma unroll
                    for (int rg = 0; rg < 2; ++rg) {
                        acc[rg][cb] = __builtin_amdgcn_mfma_f32_16x16x32_bf16(bh, xh[rg], acc[rg][cb], 0, 0, 0);
                        acc[rg][cb] = __builtin_amdgcn_mfma_f32_16x16x32_bf16(bl, xh[rg], acc[rg][cb], 0, 0, 0);
                    }
                }
                cur[0] = nxt[0]; cur[1] = nxt[1];
            }
        }

        // epilogue: packed bf16 column stores
        #pragma unroll
        for (int rg = 0; rg < 2; ++rg) {
            int row = row_base + rg * 16 + lrow;
            if (row >= N_NODES) continue;
            #pragma unroll
            for (int cb = 0; cb < 8; ++cb) {
                f32x4 a = acc[rg][cb];
                unsigned int p0 = (unsigned int)f2bf(a[0]) | (((unsigned int)f2bf(a[1])) << 16);
                unsigned int p1 = (unsigned int)f2bf(a[2]) | (((unsigned int)f2bf(a[3])) << 16);
                uint2 pv; pv.x = p0; pv.y = p1;
                *(uint2*)(Y + (size_t)row * D + cb * 16 + kgrp * 4) = pv;
            }
        }
    }
}

// ---------------------------------------------------------------------------
// Aggregate phase: one wave per node (grid-stride), half-wave edge split,
// wave-uniform scalar CSR reads, clamp + nrm=0 masking.
// ---------------------------------------------------------------------------
__device__ __forceinline__ void agg_phase(const uint2* __restrict__ Hb2,
                                          const float* __restrict__ dis,
                                          const float* __restrict__ bias,
                                          const int* __restrict__ off,
                                          const int* __restrict__ csr_src,
                                          const float* __restrict__ csr_nrm,
                                          uint2* __restrict__ AGGb2) {
    const int lane = threadIdx.x & 63;
    const int cgi  = lane & 31;
    const int half = lane >> 5;
    const int gw   = (blockIdx.x * 512 + threadIdx.x) >> 6;
    const int nw   = gridDim.x * 8;

    for (int wid = gw; wid < N_NODES; wid += nw) {
        int jb = __builtin_amdgcn_readfirstlane(off[wid]);
        int je = __builtin_amdgcn_readfirstlane(off[wid + 1]);

        float4 acc;
        {
            uint2 self = Hb2[(size_t)wid * 32 + cgi];
            float4 b = ((const float4*)bias)[cgi];
            float dn = dis[wid];
            float dn2 = dn * dn;
            acc.x = b.x + dn2 * bflo2f(self.x);
            acc.y = b.y + dn2 * bfhi2f(self.x);
            acc.z = b.z + dn2 * bflo2f(self.y);
            acc.w = b.w + dn2 * bfhi2f(self.y);
            if (half) { acc.x = 0.f; acc.y = 0.f; acc.z = 0.f; acc.w = 0.f; }
        }

        for (int base = jb; base < je; base += 8) {
            int   sv[8];
            float nv[8];
            #pragma unroll
            for (int i = 0; i < 8; ++i) {
                int j  = base + i;
                int jc = (j < je) ? j : (je - 1);
                sv[i]  = csr_src[jc];
                float n = csr_nrm[jc];
                nv[i]  = (j < je) ? n : 0.f;
            }
            uint2 g[4];
            float nn[4];
            #pragma unroll
            for (int i = 0; i < 4; ++i) {
                int s = half ? sv[i + 4] : sv[i];
                nn[i] = half ? nv[i + 4] : nv[i];
                g[i]  = Hb2[(size_t)s * 32 + cgi];
            }
            #pragma unroll
            for (int i = 0; i < 4; ++i) {
                acc.x += nn[i] * bflo2f(g[i].x);
                acc.y += nn[i] * bfhi2f(g[i].x);
                acc.z += nn[i] * bflo2f(g[i].y);
                acc.w += nn[i] * bfhi2f(g[i].y);
            }
        }

        acc.x += __shfl(acc.x, lane ^ 32);
        acc.y += __shfl(acc.y, lane ^ 32);
        acc.z += __shfl(acc.z, lane ^ 32);
        acc.w += __shfl(acc.w, lane ^ 32);

        if (half == 0) {
            uint2 o;
            o.x = (unsigned int)f2bf(acc.x) | (((unsigned int)f2bf(acc.y)) << 16);
            o.y = (unsigned int)f2bf(acc.z) | (((unsigned int)f2bf(acc.w)) << 16);
            AGGb2[(size_t)wid * 32 + cgi] = o;
        }
    }
}

// ---------------------------------------------------------------------------
// The fused cooperative kernel: entire pipeline, grid.sync() between phases.
// ---------------------------------------------------------------------------
__global__ __launch_bounds__(512, 4) void k_fused(
    const float* __restrict__ x, const int* __restrict__ ei,
    const int* __restrict__ batch,
    const float* __restrict__ W1, const float* __restrict__ b1,
    const float* __restrict__ W2, const float* __restrict__ b2,
    const float* __restrict__ Wl, const float* __restrict__ bl,
    float* __restrict__ out,
    unsigned short* HbA, unsigned short* HbB,
    float* dis, int* cnt, int* off, int* pos,
    int* chunk_sums, int* chunk_offs, int* csr_src, float* csr_nrm)
{
    __shared__ __align__(16) char smem[65536];
    cg::grid_group grid = cg::this_grid();

    const int tid  = threadIdx.x;
    const int gtid = blockIdx.x * 512 + tid;
    const int GS   = gridDim.x * 512;
    const int* srcIdx = ei;
    const int* dstIdx = ei + N_EDGES;

    // ---- P0: zero cnt ----
    for (int i = gtid; i < N_NODES; i += GS) cnt[i] = 0;
    grid.sync();

    // ---- P1: degree histogram ----
    for (int e = gtid; e < N_EDGES; e += GS) atomicAdd(&cnt[dstIdx[e]], 1);
    grid.sync();

    // ---- P2: scanA (per-chunk exclusive scan) + dis ----
    {
        int* ss = (int*)smem;
        for (int c = blockIdx.x; c < NB; c += gridDim.x) {
            int gid2 = c * CH + tid;
            int v = (gid2 < N_NODES) ? cnt[gid2] : 0;
            if (gid2 < N_NODES) dis[gid2] = rsqrtf((float)(v + 1));
            ss[tid] = v;
            __syncthreads();
            #pragma unroll
            for (int o = 1; o < CH; o <<= 1) {
                int t2 = (tid >= o) ? ss[tid - o] : 0;
                __syncthreads();
                ss[tid] += t2;
                __syncthreads();
            }
            if (gid2 < N_NODES) off[gid2] = ss[tid] - v;
            if (tid == CH - 1) chunk_sums[c] = ss[tid];
            __syncthreads();
        }
    }
    grid.sync();

    // ---- P3: scanB (chunk offsets; block 0) ----
    if (blockIdx.x == 0) {
        int* ss = (int*)smem;
        int v = (tid < NB) ? chunk_sums[tid] : 0;
        ss[tid] = v;
        __syncthreads();
        #pragma unroll
        for (int o = 1; o < CH; o <<= 1) {
            int t2 = (tid >= o) ? ss[tid - o] : 0;
            __syncthreads();
            ss[tid] += t2;
            __syncthreads();
        }
        if (tid < NB) chunk_offs[tid] = ss[tid] - v;
        if (tid == NB - 1) off[N_NODES] = ss[tid];
    }
    grid.sync();

    // ---- P4: scanC + seed pos ----
    for (int i = gtid; i < N_NODES; i += GS) {
        int v = off[i] + chunk_offs[i >> 9];   // CH = 512
        off[i] = v;
        pos[i] = v;
    }
    grid.sync();

    // ---- P5: CSR fill ----
    for (int e = gtid; e < N_EDGES; e += GS) {
        int s = srcIdx[e], d = dstIdx[e];
        int j = atomicAdd(&pos[d], 1);
        csr_src[j] = s;
        csr_nrm[j] = dis[s] * dis[d];
    }
    grid.sync();

    // ---- P6: gemm1 (fp32 x, split input, no relu) ----
    gemm_phase<0, 1>(x, W1, (short*)smem, (short*)(smem + 32768), HbA);
    grid.sync();

    // ---- P7: agg1 ----
    agg_phase((const uint2*)HbA, dis, b1, off, csr_src, csr_nrm, (uint2*)HbB);
    grid.sync();

    // ---- P8: gemm2 (bf16 input, relu fused) ----
    gemm_phase<1, 0>(HbB, W2, (short*)smem, (short*)(smem + 32768), HbA);
    grid.sync();

    // ---- P9: agg2 ----
    agg_phase((const uint2*)HbA, dis, b2, off, csr_src, csr_nrm, (uint2*)HbB);
    grid.sync();

    // ---- P10: relu + mean-pool + head (one graph per block, grid-stride) ----
    {
        const unsigned int* Hu = (const unsigned int*)HbB;
        float* shx = (float*)smem;        // 512 floats
        float* shy = shx + 512;           // 512 floats
        float* s0  = shy + 512;           // 64 floats
        float* s1  = s0 + 64;             // 64 floats
        int cp = tid & 63, q = tid >> 6;

        for (int g = blockIdx.x; g < N_GRAPHS; g += gridDim.x) {
            int lo = 0, hi = N_NODES;
            while (lo < hi) { int mid = (lo + hi) >> 1; if (batch[mid] < g) lo = mid + 1; else hi = mid; }
            int s = lo;
            lo = s; hi = N_NODES;
            while (lo < hi) { int mid = (lo + hi) >> 1; if (batch[mid] < g + 1) lo = mid + 1; else hi = mid; }
            int e = lo;

            float sx = 0.f, sy = 0.f;
            for (int i = s + q; i < e; i += 8) {
                unsigned int v = Hu[(size_t)i * 64 + cp];
                sx += fmaxf(bflo2f(v), 0.f);
                sy += fmaxf(bfhi2f(v), 0.f);
            }
            shx[q * 64 + cp] = sx;
            shy[q * 64 + cp] = sy;
            __syncthreads();

            if (tid < 64) {
                float cntf = (float)((e - s) > 0 ? (e - s) : 1);
                float px = 0.f, py = 0.f;
                #pragma unroll
                for (int r = 0; r < 8; ++r) { px += shx[r * 64 + tid]; py += shy[r * 64 + tid]; }
                px /= cntf; py /= cntf;
                s0[tid] = px * Wl[4 * tid + 0] + py * Wl[4 * tid + 2];
                s1[tid] = px * Wl[4 * tid + 1] + py * Wl[4 * tid + 3];
            }
            __syncthreads();
            #pragma unroll
            for (int o = 32; o > 0; o >>= 1) {
                if (tid < o) { s0[tid] += s0[tid + o]; s1[tid] += s1[tid + o]; }
                __syncthreads();
            }
            if (tid == 0) {
                out[g * 2 + 0] = s0[0] + bl[0];
                out[g * 2 + 1] = s1[0] + bl[1];
            }
            __syncthreads();
        }
    }
}

// ---------------------------------------------------------------------------
extern "C" void kernel_launch(void* const* d_in, const int* in_sizes, int n_in,
                              void* d_out, int out_size, void* d_ws, size_t ws_size,
                              hipStream_t stream) {
    const float* x     = (const float*)d_in[0];
    const int*   ei    = (const int*)  d_in[1];
    const int*   batch = (const int*)  d_in[2];
    const float* W1    = (const float*)d_in[3];
    const float* b1    = (const float*)d_in[4];
    const float* W2    = (const float*)d_in[5];
    const float* b2    = (const float*)d_in[6];
    const float* Wl    = (const float*)d_in[7];
    const float* bl    = (const float*)d_in[8];
    float* out = (float*)d_out;

    char* ws = (char*)d_ws;
    unsigned short* HbA = (unsigned short*)(ws);               // 25.6 MB bf16
    unsigned short* HbB = (unsigned short*)(ws + 25600000);    // 25.6 MB bf16
    float* dis        = (float*)(ws + 51200000);               // 400 KB
    int*   cnt        = (int*)  (ws + 51600000);               // 400 KB
    int*   off        = (int*)  (ws + 52000000);               // 400 KB + 16
    int*   pos        = (int*)  (ws + 52400016);               // 400 KB
    int*   chunk_sums = (int*)  (ws + 52800016);               // 1 KB
    int*   chunk_offs = (int*)  (ws + 52801040);               // 1 KB
    int*   csr_src    = (int*)  (ws + 52802064);               // 2.4 MB
    float* csr_nrm    = (float*)(ws + 55202064);               // 2.4 MB

    // co-residency-safe grid size (expected 2 blocks/CU -> 512)
    int maxb = 0;
    hipOccupancyMaxActiveBlocksPerMultiprocessor(&maxb, k_fused, 512, 0);
    if (maxb < 1) maxb = 1;
    int grid = maxb * 256;
    if (grid > 512) grid = 512;

    void* args[] = {
        (void*)&x, (void*)&ei, (void*)&batch,
        (void*)&W1, (void*)&b1, (void*)&W2, (void*)&b2, (void*)&Wl, (void*)&bl,
        (void*)&out,
        (void*)&HbA, (void*)&HbB, (void*)&dis, (void*)&cnt, (void*)&off, (void*)&pos,
        (void*)&chunk_sums, (void*)&chunk_offs, (void*)&csr_src, (void*)&csr_nrm
    };
    hipLaunchCooperativeKernel((const void*)k_fused, dim3(grid), dim3(512),
                               args, 0, stream);
}

// Round 10
// 293.539 us; speedup vs baseline: 2.9549x; 2.9549x over previous
//
#include <hip/hip_runtime.h>
#include <hip/hip_bf16.h>

#define N_NODES  100000
#define N_EDGES  600000
#define D        128
#define N_GRAPHS 512

#define CH   512
#define NB   ((N_NODES + CH - 1) / CH)

typedef __attribute__((ext_vector_type(8))) short      short8v;
typedef __attribute__((ext_vector_type(4))) float      f32x4;

// float -> bf16 (RNE) on raw bits
__device__ __forceinline__ unsigned short f2bf(float f) {
    unsigned int u = __float_as_uint(f);
    u += 0x7fffu + ((u >> 16) & 1u);
    return (unsigned short)(u >> 16);
}
__device__ __forceinline__ float bflo2f(unsigned int p) { return __uint_as_float(p << 16); }
__device__ __forceinline__ float bfhi2f(unsigned int p) { return __uint_as_float(p & 0xffff0000u); }

// ---------------------------------------------------------------------------
// k_pre: zero cnt + pre-split W1/W2 into MFMA B-fragments (bf16 hi/lo).
// Fragment t = kc*512 + cb*64 + lane, elem j: W[kc*32+(lane>>4)*8+j][cb*16+(lane&15)]
// ---------------------------------------------------------------------------
__global__ __launch_bounds__(256) void k_pre(const float* __restrict__ W1,
                                             const float* __restrict__ W2,
                                             unsigned short* __restrict__ whi1,
                                             unsigned short* __restrict__ wlo1,
                                             unsigned short* __restrict__ whi2,
                                             unsigned short* __restrict__ wlo2,
                                             int* __restrict__ cnt) {
    int tt = blockIdx.x * 256 + threadIdx.x;
    if (tt < N_NODES) cnt[tt] = 0;
    if (tt >= 4096) return;
    const float* W = (tt < 2048) ? W1 : W2;
    unsigned short* whi = (tt < 2048) ? whi1 : whi2;
    unsigned short* wlo = (tt < 2048) ? wlo1 : wlo2;
    int t = tt & 2047;

    int lane = t & 63;
    int cb   = (t >> 6) & 7;
    int kc   = t >> 9;
    int krow = kc * 32 + ((lane >> 4) * 8);
    int col  = cb * 16 + (lane & 15);

    unsigned short h8[8], l8[8];
    #pragma unroll
    for (int j = 0; j < 8; ++j) {
        float f = W[(krow + j) * D + col];
        unsigned short h = f2bf(f);
        float hf = __uint_as_float(((unsigned int)h) << 16);
        h8[j] = h;
        l8[j] = f2bf(f - hf);
    }
    #pragma unroll
    for (int j = 0; j < 8; ++j) { whi[t * 8 + j] = h8[j]; wlo[t * 8 + j] = l8[j]; }
}

__global__ void k_hist(const int* __restrict__ dst, int* __restrict__ cnt) {
    int e = blockIdx.x * blockDim.x + threadIdx.x;
    if (e < N_EDGES) atomicAdd(&cnt[dst[e]], 1);
}

// ---------------------------------------------------------------------------
// 3-pass exclusive scan of cnt -> off; scanA also emits dis; scanC seeds pos.
// ---------------------------------------------------------------------------
__global__ __launch_bounds__(CH) void k_scanA(const int* __restrict__ cnt,
                                              int* __restrict__ off,
                                              int* __restrict__ chunk_sums,
                                              float* __restrict__ dis) {
    __shared__ int s[CH];
    int tid = threadIdx.x;
    int gid = blockIdx.x * CH + tid;
    int v = (gid < N_NODES) ? cnt[gid] : 0;
    if (gid < N_NODES) dis[gid] = rsqrtf((float)(v + 1));
    s[tid] = v;
    __syncthreads();
    #pragma unroll
    for (int o = 1; o < CH; o <<= 1) {
        int t = (tid >= o) ? s[tid - o] : 0;
        __syncthreads();
        s[tid] += t;
        __syncthreads();
    }
    if (gid < N_NODES) off[gid] = s[tid] - v;
    if (tid == CH - 1) chunk_sums[blockIdx.x] = s[tid];
}

__global__ __launch_bounds__(CH) void k_scanB(const int* __restrict__ chunk_sums,
                                              int* __restrict__ chunk_offs,
                                              int* __restrict__ off) {
    __shared__ int s[CH];
    int tid = threadIdx.x;
    int v = (tid < NB) ? chunk_sums[tid] : 0;
    s[tid] = v;
    __syncthreads();
    #pragma unroll
    for (int o = 1; o < CH; o <<= 1) {
        int t = (tid >= o) ? s[tid - o] : 0;
        __syncthreads();
        s[tid] += t;
        __syncthreads();
    }
    if (tid < NB) chunk_offs[tid] = s[tid] - v;
    if (tid == NB - 1) off[N_NODES] = s[tid];
}

__global__ __launch_bounds__(CH) void k_scanC(int* __restrict__ off,
                                              const int* __restrict__ chunk_offs,
                                              int* __restrict__ pos) {
    int gid = blockIdx.x * CH + threadIdx.x;
    if (gid < N_NODES) {
        int v = off[gid] + chunk_offs[blockIdx.x];
        off[gid] = v;
        pos[gid] = v;
    }
}

// csr_nrm stores dis[src] ONLY; agg multiplies by wave-uniform dis[dst].
__global__ void k_fill(const int* __restrict__ src, const int* __restrict__ dst,
                       const float* __restrict__ dis,
                       int* __restrict__ pos,
                       int* __restrict__ csr_src, float* __restrict__ csr_nrm) {
    int e = blockIdx.x * blockDim.x + threadIdx.x;
    if (e >= N_EDGES) return;
    int s = src[e];
    int d = dst[e];
    int j = atomicAdd(&pos[d], 1);
    csr_src[j] = s;
    csr_nrm[j] = dis[s];
}

// ---------------------------------------------------------------------------
// Y[bf16] = (RELU_IN ? relu(X) : X) @ W  via 16x16x32 bf16 MFMA.
// R10: X loads issued BEFORE W staging (latency hides under the LDS copy);
// X converted to bf16-hi only (2 MFMAs: W-hi, W-lo) — per-node-random X
// rounding is averaged by the mean-pool; W stays split (systematic error).
// 512 thr / 8 waves / 256 rows per block; W fragments in 64 KB LDS.
// Operands swapped (W first) -> D holds Y^T -> packed 8-B bf16 column stores.
// ---------------------------------------------------------------------------
template<int RELU_IN, int FP32_IN>
__global__ __launch_bounds__(512) void k_gemm_mfma(const void* __restrict__ Xv,
                                                   const unsigned short* __restrict__ whi,
                                                   const unsigned short* __restrict__ wlo,
                                                   unsigned short* __restrict__ Y) {
    __shared__ short wl_hi[16384];   // 32 KB
    __shared__ short wl_lo[16384];   // 32 KB

    const int tid  = threadIdx.x;
    const int wave = tid >> 6;
    const int lane = tid & 63;
    const int lrow = lane & 15;
    const int kgrp = lane >> 4;
    const int row_base = blockIdx.x * 256 + wave * 32;

    const float*          Xf = (const float*)Xv;
    const unsigned short* Xb = (const unsigned short*)Xv;

    // ---- issue all X loads first (latency overlapped with W staging) ----
    float4  xr[4][2][2];   // FP32_IN
    short8v xrb[4][2];     // bf16 in
    #pragma unroll
    for (int kc = 0; kc < 4; ++kc)
        #pragma unroll
        for (int rg = 0; rg < 2; ++rg) {
            const int row = row_base + rg * 16 + lrow;
            if (FP32_IN) {
                if (row < N_NODES) {
                    const float* p = Xf + (size_t)row * D + kc * 32 + kgrp * 8;
                    xr[kc][rg][0] = *(const float4*)p;
                    xr[kc][rg][1] = *(const float4*)(p + 4);
                } else {
                    xr[kc][rg][0] = make_float4(0.f, 0.f, 0.f, 0.f);
                    xr[kc][rg][1] = make_float4(0.f, 0.f, 0.f, 0.f);
                }
            } else {
                short8v v = {0, 0, 0, 0, 0, 0, 0, 0};
                if (row < N_NODES)
                    v = *(const short8v*)(Xb + (size_t)row * D + kc * 32 + kgrp * 8);
                xrb[kc][rg] = v;
            }
        }

    // ---- stage W fragments (linear float4 copy of precomputed frags) ----
    {
        const float4* sh = (const float4*)whi;
        const float4* sl = (const float4*)wlo;
        float4* dh = (float4*)wl_hi;
        float4* dl = (float4*)wl_lo;
        #pragma unroll
        for (int i = tid; i < 2048; i += 512) { dh[i] = sh[i]; dl[i] = sl[i]; }
    }
    __syncthreads();

    f32x4 acc[2][8];
    #pragma unroll
    for (int rg = 0; rg < 2; ++rg)
        #pragma unroll
        for (int cb = 0; cb < 8; ++cb)
            acc[rg][cb] = (f32x4){0.f, 0.f, 0.f, 0.f};

    #pragma unroll
    for (int kc = 0; kc < 4; ++kc) {
        short8v xh[2];
        #pragma unroll
        for (int rg = 0; rg < 2; ++rg) {
            if (FP32_IN) {
                float fv[8] = {xr[kc][rg][0].x, xr[kc][rg][0].y, xr[kc][rg][0].z, xr[kc][rg][0].w,
                               xr[kc][rg][1].x, xr[kc][rg][1].y, xr[kc][rg][1].z, xr[kc][rg][1].w};
                #pragma unroll
                for (int j = 0; j < 8; ++j) {
                    float f = RELU_IN ? fmaxf(fv[j], 0.f) : fv[j];
                    xh[rg][j] = (short)f2bf(f);
                }
            } else {
                short8v v = xrb[kc][rg];
                if (RELU_IN) {
                    #pragma unroll
                    for (int j = 0; j < 8; ++j)
                        if (((unsigned short)v[j]) & 0x8000u) v[j] = 0;
                }
                xh[rg] = v;
            }
        }
        #pragma unroll
        for (int cb = 0; cb < 8; ++cb) {
            const int fo = ((kc * 8 + cb) * 64 + lane) * 8;
            short8v bh = *(const short8v*)&wl_hi[fo];
            short8v bl = *(const short8v*)&wl_lo[fo];
            #pragma unroll
            for (int rg = 0; rg < 2; ++rg) {
                acc[rg][cb] = __builtin_amdgcn_mfma_f32_16x16x32_bf16(bh, xh[rg], acc[rg][cb], 0, 0, 0);
                acc[rg][cb] = __builtin_amdgcn_mfma_f32_16x16x32_bf16(bl, xh[rg], acc[rg][cb], 0, 0, 0);
            }
        }
    }

    #pragma unroll
    for (int rg = 0; rg < 2; ++rg) {
        const int row = row_base + rg * 16 + lrow;
        if (row >= N_NODES) continue;
        #pragma unroll
        for (int cb = 0; cb < 8; ++cb) {
            f32x4 a = acc[rg][cb];
            unsigned int p0 = (unsigned int)f2bf(a[0]) | (((unsigned int)f2bf(a[1])) << 16);
            unsigned int p1 = (unsigned int)f2bf(a[2]) | (((unsigned int)f2bf(a[3])) << 16);
            uint2 pv; pv.x = p0; pv.y = p1;
            *(uint2*)(Y + (size_t)row * D + cb * 16 + kgrp * 4) = pv;
        }
    }
}

// ---------------------------------------------------------------------------
// Gather-aggregate: one wave per node, half-wave edge split, wave-uniform
// scalar CSR reads. csr_nrm holds dis[src]; multiply by dn (=dis[dst]) here.
// ---------------------------------------------------------------------------
__global__ __launch_bounds__(256) void k_agg(const uint2* __restrict__ Hb2,
                                             const float* __restrict__ dis,
                                             const float* __restrict__ bias,
                                             const int* __restrict__ off,
                                             const int* __restrict__ csr_src,
                                             const float* __restrict__ csr_nrm,
                                             uint2* __restrict__ AGGb2) {
    int wid = (blockIdx.x * 256 + threadIdx.x) >> 6;
    if (wid >= N_NODES) return;
    int lane = threadIdx.x & 63;
    int cg   = lane & 31;
    int half = lane >> 5;

    int jb = __builtin_amdgcn_readfirstlane(off[wid]);
    int je = __builtin_amdgcn_readfirstlane(off[wid + 1]);

    float dn = dis[wid];
    float4 acc;
    {
        uint2 self = Hb2[(size_t)wid * 32 + cg];
        float4 b = ((const float4*)bias)[cg];
        float dn2 = dn * dn;
        acc.x = b.x + dn2 * bflo2f(self.x);
        acc.y = b.y + dn2 * bfhi2f(self.x);
        acc.z = b.z + dn2 * bflo2f(self.y);
        acc.w = b.w + dn2 * bfhi2f(self.y);
        if (half) { acc.x = 0.f; acc.y = 0.f; acc.z = 0.f; acc.w = 0.f; }
    }

    for (int base = jb; base < je; base += 8) {
        int   sv[8];
        float nv[8];
        #pragma unroll
        for (int i = 0; i < 8; ++i) {
            int j  = base + i;
            int jc = (j < je) ? j : (je - 1);
            sv[i]  = csr_src[jc];               // uniform -> s_load
            float n = csr_nrm[jc];              // uniform -> s_load (dis[src])
            nv[i]  = (j < je) ? n * dn : 0.f;
        }
        uint2 g[4];
        float nn[4];
        #pragma unroll
        for (int i = 0; i < 4; ++i) {
            int s = half ? sv[i + 4] : sv[i];
            nn[i] = half ? nv[i + 4] : nv[i];
            g[i]  = Hb2[(size_t)s * 32 + cg];
        }
        #pragma unroll
        for (int i = 0; i < 4; ++i) {
            acc.x += nn[i] * bflo2f(g[i].x);
            acc.y += nn[i] * bfhi2f(g[i].x);
            acc.z += nn[i] * bflo2f(g[i].y);
            acc.w += nn[i] * bfhi2f(g[i].y);
        }
    }

    acc.x += __shfl(acc.x, lane ^ 32);
    acc.y += __shfl(acc.y, lane ^ 32);
    acc.z += __shfl(acc.z, lane ^ 32);
    acc.w += __shfl(acc.w, lane ^ 32);

    if (half == 0) {
        uint2 o;
        o.x = (unsigned int)f2bf(acc.x) | (((unsigned int)f2bf(acc.y)) << 16);
        o.y = (unsigned int)f2bf(acc.z) | (((unsigned int)f2bf(acc.w)) << 16);
        AGGb2[(size_t)wid * 32 + cg] = o;
    }
}

// ---------------------------------------------------------------------------
// One block (512 thr) per graph: relu + mean-pool + linear head.
// ---------------------------------------------------------------------------
__global__ __launch_bounds__(512) void k_pool_head(const unsigned int* __restrict__ Hu,
                                                   const int* __restrict__ batch,
                                                   const float* __restrict__ Wl,
                                                   const float* __restrict__ bl,
                                                   float* __restrict__ out) {
    int g   = blockIdx.x;
    int tid = threadIdx.x;
    int cp  = tid & 63;
    int q   = tid >> 6;

    int lo = 0, hi = N_NODES;
    while (lo < hi) { int mid = (lo + hi) >> 1; if (batch[mid] < g) lo = mid + 1; else hi = mid; }
    int s = lo;
    lo = s; hi = N_NODES;
    while (lo < hi) { int mid = (lo + hi) >> 1; if (batch[mid] < g + 1) lo = mid + 1; else hi = mid; }
    int e = lo;

    float sx = 0.f, sy = 0.f;
    for (int i = s + q; i < e; i += 8) {
        unsigned int v = Hu[(size_t)i * 64 + cp];
        sx += fmaxf(bflo2f(v), 0.f);
        sy += fmaxf(bfhi2f(v), 0.f);
    }

    __shared__ float shx[8][64];
    __shared__ float shy[8][64];
    shx[q][cp] = sx;
    shy[q][cp] = sy;
    __syncthreads();

    __shared__ float s0[64];
    __shared__ float s1[64];
    if (tid < 64) {
        float cnt = (float)((e - s) > 0 ? (e - s) : 1);
        float px = 0.f, py = 0.f;
        #pragma unroll
        for (int r = 0; r < 8; ++r) { px += shx[r][tid]; py += shy[r][tid]; }
        px /= cnt; py /= cnt;
        s0[tid] = px * Wl[4 * tid + 0] + py * Wl[4 * tid + 2];
        s1[tid] = px * Wl[4 * tid + 1] + py * Wl[4 * tid + 3];
    }
    __syncthreads();
    #pragma unroll
    for (int o = 32; o > 0; o >>= 1) {
        if (tid < o) { s0[tid] += s0[tid + o]; s1[tid] += s1[tid + o]; }
        __syncthreads();
    }
    if (tid == 0) {
        out[g * 2 + 0] = s0[0] + bl[0];
        out[g * 2 + 1] = s1[0] + bl[1];
    }
}

// ---------------------------------------------------------------------------
extern "C" void kernel_launch(void* const* d_in, const int* in_sizes, int n_in,
                              void* d_out, int out_size, void* d_ws, size_t ws_size,
                              hipStream_t stream) {
    const float* x     = (const float*)d_in[0];
    const int*   ei    = (const int*)  d_in[1];
    const int*   batch = (const int*)  d_in[2];
    const float* W1    = (const float*)d_in[3];
    const float* b1    = (const float*)d_in[4];
    const float* W2    = (const float*)d_in[5];
    const float* b2    = (const float*)d_in[6];
    const float* Wl    = (const float*)d_in[7];
    const float* bl    = (const float*)d_in[8];
    float* out = (float*)d_out;

    char* ws = (char*)d_ws;
    unsigned short* HbA = (unsigned short*)(ws);               // 25.6 MB bf16
    unsigned short* HbB = (unsigned short*)(ws + 25600000);    // 25.6 MB bf16
    float* dis        = (float*)(ws + 51200000);               // 400 KB
    int*   cnt        = (int*)  (ws + 51600000);               // 400 KB
    int*   off        = (int*)  (ws + 52000000);               // 400 KB + 16
    int*   pos        = (int*)  (ws + 52400016);               // 400 KB
    int*   chunk_sums = (int*)  (ws + 52800016);               // 1 KB
    int*   chunk_offs = (int*)  (ws + 52801040);               // 1 KB
    int*   csr_src    = (int*)  (ws + 52802064);               // 2.4 MB
    float* csr_nrm    = (float*)(ws + 55202064);               // 2.4 MB
    unsigned short* whi1 = (unsigned short*)(ws + 57602064);   // 32 KB
    unsigned short* wlo1 = (unsigned short*)(ws + 57634832);   // 32 KB
    unsigned short* whi2 = (unsigned short*)(ws + 57667600);   // 32 KB
    unsigned short* wlo2 = (unsigned short*)(ws + 57700368);   // 32 KB

    const int* srcIdx = ei;
    const int* dstIdx = ei + N_EDGES;

    // ---- pre: zero cnt + W split (one launch) ----
    k_pre <<<(N_NODES + 255) / 256, 256, 0, stream>>>(W1, W2, whi1, wlo1, whi2, wlo2, cnt);
    // ---- CSR build ----
    k_hist <<<(N_EDGES + 255) / 256, 256, 0, stream>>>(dstIdx, cnt);
    k_scanA<<<NB, CH, 0, stream>>>(cnt, off, chunk_sums, dis);
    k_scanB<<<1,  CH, 0, stream>>>(chunk_sums, chunk_offs, off);
    k_scanC<<<NB, CH, 0, stream>>>(off, chunk_offs, pos);
    k_fill <<<(N_EDGES + 255) / 256, 256, 0, stream>>>(srcIdx, dstIdx, dis, pos,
                                                       csr_src, csr_nrm);

    const int gemm_grid = (N_NODES + 255) / 256;   // 391 blocks, 256 rows each
    const int agg_grid  = (N_NODES * 64 + 255) / 256;

    // ---- layer 1 ----
    k_gemm_mfma<0, 1><<<gemm_grid, 512, 0, stream>>>(x, whi1, wlo1, HbA);
    k_agg<<<agg_grid, 256, 0, stream>>>((const uint2*)HbA, dis, b1, off,
                                        csr_src, csr_nrm, (uint2*)HbB);
    // ---- layer 2 (relu fused into GEMM input) ----
    k_gemm_mfma<1, 0><<<gemm_grid, 512, 0, stream>>>(HbB, whi2, wlo2, HbA);
    k_agg<<<agg_grid, 256, 0, stream>>>((const uint2*)HbA, dis, b2, off,
                                        csr_src, csr_nrm, (uint2*)HbB);
    // ---- relu + mean-pool + head ----
    k_pool_head<<<N_GRAPHS, 512, 0, stream>>>((const unsigned int*)HbB, batch, Wl, bl, out);
}

// Round 11
// 282.613 us; speedup vs baseline: 3.0691x; 1.0387x over previous
//
#include <hip/hip_runtime.h>
#include <hip/hip_bf16.h>

#define N_NODES  100000
#define N_EDGES  600000
#define D        128
#define N_GRAPHS 512

#define CH   512
#define NB   ((N_NODES + CH - 1) / CH)   // 196

#define GEMM_GRID  ((N_NODES + 127) / 128)   // 782 blocks, 128 rows each
#define HIST_BLOCKS 160

typedef __attribute__((ext_vector_type(8))) short      short8v;
typedef __attribute__((ext_vector_type(4))) float      f32x4;

// float -> bf16 (RNE) on raw bits
__device__ __forceinline__ unsigned short f2bf(float f) {
    unsigned int u = __float_as_uint(f);
    u += 0x7fffu + ((u >> 16) & 1u);
    return (unsigned short)(u >> 16);
}
__device__ __forceinline__ float bflo2f(unsigned int p) { return __uint_as_float(p << 16); }
__device__ __forceinline__ float bfhi2f(unsigned int p) { return __uint_as_float(p & 0xffff0000u); }

// ---------------------------------------------------------------------------
// k_pre: zero cnt + pre-split W1/W2 into MFMA A-operand fragments (bf16 hi/lo).
// Fragment t = kc*512 + cb*64 + lane, elem j: W[kc*32+(lane>>4)*8+j][cb*16+(lane&15)]
// Fragment loads in the GEMM are 64-lane x 16 B = 1 KB contiguous (coalesced).
// ---------------------------------------------------------------------------
__global__ __launch_bounds__(256) void k_pre(const float* __restrict__ W1,
                                             const float* __restrict__ W2,
                                             unsigned short* __restrict__ whi1,
                                             unsigned short* __restrict__ wlo1,
                                             unsigned short* __restrict__ whi2,
                                             unsigned short* __restrict__ wlo2,
                                             int* __restrict__ cnt) {
    int tt = blockIdx.x * 256 + threadIdx.x;
    if (tt < N_NODES) cnt[tt] = 0;
    if (tt >= 4096) return;
    const float* W = (tt < 2048) ? W1 : W2;
    unsigned short* whi = (tt < 2048) ? whi1 : whi2;
    unsigned short* wlo = (tt < 2048) ? wlo1 : wlo2;
    int t = tt & 2047;

    int lane = t & 63;
    int cb   = (t >> 6) & 7;
    int kc   = t >> 9;
    int krow = kc * 32 + ((lane >> 4) * 8);
    int col  = cb * 16 + (lane & 15);

    unsigned short h8[8], l8[8];
    #pragma unroll
    for (int j = 0; j < 8; ++j) {
        float f = W[(krow + j) * D + col];
        unsigned short h = f2bf(f);
        float hf = __uint_as_float(((unsigned int)h) << 16);
        h8[j] = h;
        l8[j] = f2bf(f - hf);
    }
    #pragma unroll
    for (int j = 0; j < 8; ++j) { whi[t * 8 + j] = h8[j]; wlo[t * 8 + j] = l8[j]; }
}

// ---------------------------------------------------------------------------
// Barrier-free GEMM tile: 256 thr / 4 waves / 128 rows. W fragments are read
// straight from global (L2-broadcast: 64 KB shared by all waves) — no LDS,
// no __syncthreads, waves free-run. X held in registers (bf16-hi only; the
// per-node-random X rounding is averaged by the 195-node mean-pool; W stays
// hi+lo split since its error is systematic).
// Operands swapped (W first) -> D holds Y^T -> packed 8-B bf16 column stores.
// ---------------------------------------------------------------------------
template<int RELU_IN, int FP32_IN>
__device__ __forceinline__ void gemm_tile(int tile, const void* __restrict__ Xv,
                                          const unsigned short* __restrict__ whi,
                                          const unsigned short* __restrict__ wlo,
                                          unsigned short* __restrict__ Y) {
    const int tid  = threadIdx.x;
    const int wave = tid >> 6;           // 0..3
    const int lane = tid & 63;
    const int lrow = lane & 15;
    const int kgrp = lane >> 4;          // 0..3
    const int row_base = tile * 128 + wave * 32;

    // ---- X into registers, bf16-hi ----
    short8v xh[4][2];
    if (FP32_IN) {
        const float* Xf = (const float*)Xv;
        #pragma unroll
        for (int kc = 0; kc < 4; ++kc)
            #pragma unroll
            for (int rg = 0; rg < 2; ++rg) {
                const int row = row_base + rg * 16 + lrow;
                float4 a = make_float4(0.f, 0.f, 0.f, 0.f);
                float4 b = make_float4(0.f, 0.f, 0.f, 0.f);
                if (row < N_NODES) {
                    const float* p = Xf + (size_t)row * D + kc * 32 + kgrp * 8;
                    a = *(const float4*)p;
                    b = *(const float4*)(p + 4);
                }
                float fv[8] = {a.x, a.y, a.z, a.w, b.x, b.y, b.z, b.w};
                #pragma unroll
                for (int j = 0; j < 8; ++j) {
                    float f = RELU_IN ? fmaxf(fv[j], 0.f) : fv[j];
                    xh[kc][rg][j] = (short)f2bf(f);
                }
            }
    } else {
        const unsigned short* Xb = (const unsigned short*)Xv;
        #pragma unroll
        for (int kc = 0; kc < 4; ++kc)
            #pragma unroll
            for (int rg = 0; rg < 2; ++rg) {
                const int row = row_base + rg * 16 + lrow;
                short8v v = {0, 0, 0, 0, 0, 0, 0, 0};
                if (row < N_NODES)
                    v = *(const short8v*)(Xb + (size_t)row * D + kc * 32 + kgrp * 8);
                if (RELU_IN) {
                    #pragma unroll
                    for (int j = 0; j < 8; ++j)
                        if (((unsigned short)v[j]) & 0x8000u) v[j] = 0;
                }
                xh[kc][rg] = v;
            }
    }

    f32x4 acc[2][8];
    #pragma unroll
    for (int rg = 0; rg < 2; ++rg)
        #pragma unroll
        for (int cb = 0; cb < 8; ++cb)
            acc[rg][cb] = (f32x4){0.f, 0.f, 0.f, 0.f};

    // ---- MFMA stream; W frags loaded from global (L2-hot), fully unrolled
    //      so the compiler hoists loads ahead within the VGPR budget ----
    #pragma unroll
    for (int kc = 0; kc < 4; ++kc) {
        #pragma unroll
        for (int cb = 0; cb < 8; ++cb) {
            const int fo = ((kc * 8 + cb) * 64 + lane) * 8;
            short8v bh = *(const short8v*)&whi[fo];
            short8v bl = *(const short8v*)&wlo[fo];
            acc[0][cb] = __builtin_amdgcn_mfma_f32_16x16x32_bf16(bh, xh[kc][0], acc[0][cb], 0, 0, 0);
            acc[1][cb] = __builtin_amdgcn_mfma_f32_16x16x32_bf16(bh, xh[kc][1], acc[1][cb], 0, 0, 0);
            acc[0][cb] = __builtin_amdgcn_mfma_f32_16x16x32_bf16(bl, xh[kc][0], acc[0][cb], 0, 0, 0);
            acc[1][cb] = __builtin_amdgcn_mfma_f32_16x16x32_bf16(bl, xh[kc][1], acc[1][cb], 0, 0, 0);
        }
    }

    #pragma unroll
    for (int rg = 0; rg < 2; ++rg) {
        const int row = row_base + rg * 16 + lrow;
        if (row >= N_NODES) continue;
        #pragma unroll
        for (int cb = 0; cb < 8; ++cb) {
            f32x4 a = acc[rg][cb];
            unsigned int p0 = (unsigned int)f2bf(a[0]) | (((unsigned int)f2bf(a[1])) << 16);
            unsigned int p1 = (unsigned int)f2bf(a[2]) | (((unsigned int)f2bf(a[3])) << 16);
            uint2 pv; pv.x = p0; pv.y = p1;
            *(uint2*)(Y + (size_t)row * D + cb * 16 + kgrp * 4) = pv;
        }
    }
}

// gemm1 (fp32 in, no relu) with the degree histogram fused into spare blocks
__global__ __launch_bounds__(256) void k_gemm1_hist(const float* __restrict__ x,
                                                    const unsigned short* __restrict__ whi1,
                                                    const unsigned short* __restrict__ wlo1,
                                                    unsigned short* __restrict__ HbA,
                                                    const int* __restrict__ dstIdx,
                                                    int* __restrict__ cnt) {
    if (blockIdx.x < GEMM_GRID) {
        gemm_tile<0, 1>(blockIdx.x, x, whi1, wlo1, HbA);
    } else {
        int b = blockIdx.x - GEMM_GRID;
        for (int e = b * 256 + threadIdx.x; e < N_EDGES; e += HIST_BLOCKS * 256)
            atomicAdd(&cnt[dstIdx[e]], 1);
    }
}

// gemm2: bf16 input, relu fused
__global__ __launch_bounds__(256) void k_gemm2(const unsigned short* __restrict__ Xb,
                                               const unsigned short* __restrict__ whi2,
                                               const unsigned short* __restrict__ wlo2,
                                               unsigned short* __restrict__ HbA) {
    gemm_tile<1, 0>(blockIdx.x, Xb, whi2, wlo2, HbA);
}

// ---------------------------------------------------------------------------
// scanA: per-chunk exclusive scan of cnt -> off(local), chunk_sums; emits dis.
// ---------------------------------------------------------------------------
__global__ __launch_bounds__(CH) void k_scanA(const int* __restrict__ cnt,
                                              int* __restrict__ off,
                                              int* __restrict__ chunk_sums,
                                              float* __restrict__ dis) {
    __shared__ int s[CH];
    int tid = threadIdx.x;
    int gid = blockIdx.x * CH + tid;
    int v = (gid < N_NODES) ? cnt[gid] : 0;
    if (gid < N_NODES) dis[gid] = rsqrtf((float)(v + 1));
    s[tid] = v;
    __syncthreads();
    #pragma unroll
    for (int o = 1; o < CH; o <<= 1) {
        int t = (tid >= o) ? s[tid - o] : 0;
        __syncthreads();
        s[tid] += t;
        __syncthreads();
    }
    if (gid < N_NODES) off[gid] = s[tid] - v;
    if (tid == CH - 1) chunk_sums[blockIdx.x] = s[tid];
}

// ---------------------------------------------------------------------------
// scanBC: each block redundantly scans the 196 chunk sums in LDS, picks its
// own chunk offset, applies it, and seeds pos. Replaces scanB + scanC.
// ---------------------------------------------------------------------------
__global__ __launch_bounds__(CH) void k_scanBC(int* __restrict__ off,
                                               const int* __restrict__ chunk_sums,
                                               int* __restrict__ pos) {
    __shared__ int s[CH];
    __shared__ int addsh;
    int tid = threadIdx.x;
    int v = (tid < NB) ? chunk_sums[tid] : 0;
    s[tid] = v;
    __syncthreads();
    #pragma unroll
    for (int o = 1; o < CH; o <<= 1) {
        int t = (tid >= o) ? s[tid - o] : 0;
        __syncthreads();
        s[tid] += t;
        __syncthreads();
    }
    if (tid == blockIdx.x) addsh = s[tid] - v;   // exclusive prefix at my chunk
    __syncthreads();
    int add = addsh;
    int gid = blockIdx.x * CH + tid;
    if (gid < N_NODES) {
        int w = off[gid] + add;
        off[gid] = w;
        pos[gid] = w;
    }
    if (blockIdx.x == 0 && tid == 0) off[N_NODES] = N_EDGES;  // total in-degree
}

// ---------------------------------------------------------------------------
// CSR fill: ONE packed 8-B scatter per edge: {src, dis[src] bits}.
// ---------------------------------------------------------------------------
__global__ void k_fill(const int* __restrict__ src, const int* __restrict__ dst,
                       const float* __restrict__ dis,
                       int* __restrict__ pos, int2* __restrict__ csr) {
    int e = blockIdx.x * blockDim.x + threadIdx.x;
    if (e >= N_EDGES) return;
    int s = src[e];
    int d = dst[e];
    int j = atomicAdd(&pos[d], 1);
    int2 v;
    v.x = s;
    v.y = __float_as_int(dis[s]);
    csr[j] = v;
}

// ---------------------------------------------------------------------------
// Gather-aggregate: one wave per node, half-wave edge split, wave-uniform
// scalar CSR reads (packed int2). csr.y holds dis[src]; multiply by dn here.
// ---------------------------------------------------------------------------
__global__ __launch_bounds__(256) void k_agg(const uint2* __restrict__ Hb2,
                                             const float* __restrict__ dis,
                                             const float* __restrict__ bias,
                                             const int* __restrict__ off,
                                             const int2* __restrict__ csr,
                                             uint2* __restrict__ AGGb2) {
    int wid = (blockIdx.x * 256 + threadIdx.x) >> 6;
    if (wid >= N_NODES) return;
    int lane = threadIdx.x & 63;
    int cg   = lane & 31;
    int half = lane >> 5;

    int jb = __builtin_amdgcn_readfirstlane(off[wid]);
    int je = __builtin_amdgcn_readfirstlane(off[wid + 1]);

    float dn = dis[wid];
    float4 acc;
    {
        uint2 self = Hb2[(size_t)wid * 32 + cg];
        float4 b = ((const float4*)bias)[cg];
        float dn2 = dn * dn;
        acc.x = b.x + dn2 * bflo2f(self.x);
        acc.y = b.y + dn2 * bfhi2f(self.x);
        acc.z = b.z + dn2 * bflo2f(self.y);
        acc.w = b.w + dn2 * bfhi2f(self.y);
        if (half) { acc.x = 0.f; acc.y = 0.f; acc.z = 0.f; acc.w = 0.f; }
    }

    for (int base = jb; base < je; base += 8) {
        int   sv[8];
        float nv[8];
        #pragma unroll
        for (int i = 0; i < 8; ++i) {
            int j  = base + i;
            int jc = (j < je) ? j : (je - 1);
            int2 c2 = csr[jc];                  // uniform -> s_load_dwordx2
            sv[i]  = c2.x;
            nv[i]  = (j < je) ? __int_as_float(c2.y) * dn : 0.f;
        }
        uint2 g[4];
        float nn[4];
        #pragma unroll
        for (int i = 0; i < 4; ++i) {
            int s = half ? sv[i + 4] : sv[i];
            nn[i] = half ? nv[i + 4] : nv[i];
            g[i]  = Hb2[(size_t)s * 32 + cg];
        }
        #pragma unroll
        for (int i = 0; i < 4; ++i) {
            acc.x += nn[i] * bflo2f(g[i].x);
            acc.y += nn[i] * bfhi2f(g[i].x);
            acc.z += nn[i] * bflo2f(g[i].y);
            acc.w += nn[i] * bfhi2f(g[i].y);
        }
    }

    acc.x += __shfl(acc.x, lane ^ 32);
    acc.y += __shfl(acc.y, lane ^ 32);
    acc.z += __shfl(acc.z, lane ^ 32);
    acc.w += __shfl(acc.w, lane ^ 32);

    if (half == 0) {
        uint2 o;
        o.x = (unsigned int)f2bf(acc.x) | (((unsigned int)f2bf(acc.y)) << 16);
        o.y = (unsigned int)f2bf(acc.z) | (((unsigned int)f2bf(acc.w)) << 16);
        AGGb2[(size_t)wid * 32 + cg] = o;
    }
}

// ---------------------------------------------------------------------------
// One block (512 thr) per graph: relu + mean-pool + linear head.
// ---------------------------------------------------------------------------
__global__ __launch_bounds__(512) void k_pool_head(const unsigned int* __restrict__ Hu,
                                                   const int* __restrict__ batch,
                                                   const float* __restrict__ Wl,
                                                   const float* __restrict__ bl,
                                                   float* __restrict__ out) {
    int g   = blockIdx.x;
    int tid = threadIdx.x;
    int cp  = tid & 63;
    int q   = tid >> 6;

    int lo = 0, hi = N_NODES;
    while (lo < hi) { int mid = (lo + hi) >> 1; if (batch[mid] < g) lo = mid + 1; else hi = mid; }
    int s = lo;
    lo = s; hi = N_NODES;
    while (lo < hi) { int mid = (lo + hi) >> 1; if (batch[mid] < g + 1) lo = mid + 1; else hi = mid; }
    int e = lo;

    float sx = 0.f, sy = 0.f;
    for (int i = s + q; i < e; i += 8) {
        unsigned int v = Hu[(size_t)i * 64 + cp];
        sx += fmaxf(bflo2f(v), 0.f);
        sy += fmaxf(bfhi2f(v), 0.f);
    }

    __shared__ float shx[8][64];
    __shared__ float shy[8][64];
    shx[q][cp] = sx;
    shy[q][cp] = sy;
    __syncthreads();

    __shared__ float s0[64];
    __shared__ float s1[64];
    if (tid < 64) {
        float cnt = (float)((e - s) > 0 ? (e - s) : 1);
        float px = 0.f, py = 0.f;
        #pragma unroll
        for (int r = 0; r < 8; ++r) { px += shx[r][tid]; py += shy[r][tid]; }
        px /= cnt; py /= cnt;
        s0[tid] = px * Wl[4 * tid + 0] + py * Wl[4 * tid + 2];
        s1[tid] = px * Wl[4 * tid + 1] + py * Wl[4 * tid + 3];
    }
    __syncthreads();
    #pragma unroll
    for (int o = 32; o > 0; o >>= 1) {
        if (tid < o) { s0[tid] += s0[tid + o]; s1[tid] += s1[tid + o]; }
        __syncthreads();
    }
    if (tid == 0) {
        out[g * 2 + 0] = s0[0] + bl[0];
        out[g * 2 + 1] = s1[0] + bl[1];
    }
}

// ---------------------------------------------------------------------------
extern "C" void kernel_launch(void* const* d_in, const int* in_sizes, int n_in,
                              void* d_out, int out_size, void* d_ws, size_t ws_size,
                              hipStream_t stream) {
    const float* x     = (const float*)d_in[0];
    const int*   ei    = (const int*)  d_in[1];
    const int*   batch = (const int*)  d_in[2];
    const float* W1    = (const float*)d_in[3];
    const float* b1    = (const float*)d_in[4];
    const float* W2    = (const float*)d_in[5];
    const float* b2    = (const float*)d_in[6];
    const float* Wl    = (const float*)d_in[7];
    const float* bl    = (const float*)d_in[8];
    float* out = (float*)d_out;

    char* ws = (char*)d_ws;
    unsigned short* HbA = (unsigned short*)(ws);               // 25.6 MB bf16
    unsigned short* HbB = (unsigned short*)(ws + 25600000);    // 25.6 MB bf16
    float* dis        = (float*)(ws + 51200000);               // 400 KB
    int*   cnt        = (int*)  (ws + 51600000);               // 400 KB
    int*   off        = (int*)  (ws + 52000000);               // 400 KB + 16
    int*   pos        = (int*)  (ws + 52400016);               // 400 KB
    int*   chunk_sums = (int*)  (ws + 52800016);               // 1 KB
    int2*  csr        = (int2*) (ws + 52801040);               // 4.8 MB (8B-aligned)
    unsigned short* whi1 = (unsigned short*)(ws + 57601040);   // 32 KB
    unsigned short* wlo1 = (unsigned short*)(ws + 57633808);   // 32 KB
    unsigned short* whi2 = (unsigned short*)(ws + 57666576);   // 32 KB
    unsigned short* wlo2 = (unsigned short*)(ws + 57699344);   // 32 KB

    const int* srcIdx = ei;
    const int* dstIdx = ei + N_EDGES;

    // 1) zero cnt + W split
    k_pre <<<(N_NODES + 255) / 256, 256, 0, stream>>>(W1, W2, whi1, wlo1, whi2, wlo2, cnt);
    // 2) gemm1 (barrier-free) with degree histogram fused into spare blocks
    k_gemm1_hist<<<GEMM_GRID + HIST_BLOCKS, 256, 0, stream>>>(x, whi1, wlo1, HbA, dstIdx, cnt);
    // 3-4) scan
    k_scanA <<<NB, CH, 0, stream>>>(cnt, off, chunk_sums, dis);
    k_scanBC<<<NB, CH, 0, stream>>>(off, chunk_sums, pos);
    // 5) CSR fill (packed 8-B scatter)
    k_fill <<<(N_EDGES + 255) / 256, 256, 0, stream>>>(srcIdx, dstIdx, dis, pos, csr);

    const int agg_grid = (N_NODES * 64 + 255) / 256;

    // 6) agg layer 1
    k_agg<<<agg_grid, 256, 0, stream>>>((const uint2*)HbA, dis, b1, off, csr, (uint2*)HbB);
    // 7) gemm2 (relu fused)
    k_gemm2<<<GEMM_GRID, 256, 0, stream>>>(HbB, whi2, wlo2, HbA);
    // 8) agg layer 2
    k_agg<<<agg_grid, 256, 0, stream>>>((const uint2*)HbA, dis, b2, off, csr, (uint2*)HbB);
    // 9) relu + mean-pool + head
    k_pool_head<<<N_GRAPHS, 512, 0, stream>>>((const unsigned int*)HbB, batch, Wl, bl, out);
}